// Round 1
// 330.898 us; speedup vs baseline: 1.0619x; 1.0619x over previous
//
#include <hip/hip_runtime.h>
#include <math.h>

#define VOCAB 50000
#define DW 300
#define DH 50
#define G4 200
#define BATCH 1024
#define TMAX 200
#define OUTC 4

// ---------------------------------------------------------------------------
// Kernel 0: transpose w_ih [200][300] -> w_T [300][200] (so proj reads are
// coalesced across the N dimension on the VMEM pipe).
__global__ __launch_bounds__(256) void transpose_wih(
    const float* __restrict__ w_ih, float* __restrict__ w_T)
{
    int i = blockIdx.x * 256 + threadIdx.x;
    if (i < G4 * DW) {
        int u = i / DW, k = i % DW;
        w_T[k * G4 + u] = w_ih[i];
    }
}

// ---------------------------------------------------------------------------
// Kernel A: emb_proj[v][u2] = sum_k emb[v][k]*w_ih[u][k] + b_ih[u] + b_hh[u]
// with gate-permuted columns u2 = (u%50)*4 + u/50 (unit-major, gate-minor).
// Unchanged from previous round (proj gets its own tuning pass next round).
__global__ __launch_bounds__(256, 2) void proj_kernel(
    const float* __restrict__ emb, const float* __restrict__ w_T,
    const float* __restrict__ b_ih, const float* __restrict__ b_hh,
    float* __restrict__ emb_proj)
{
    __shared__ __align__(16) float e_s[100 * 108];  // rows padded to 108 dwords
    const int tid = threadIdx.x;
    const int v0 = blockIdx.x * 100;
    const int m_idx = tid / 25;   // 0..9 (valid for tid<250)
    const int n_idx = tid % 25;   // 0..24

    float acc[10][8];
#pragma unroll
    for (int m = 0; m < 10; m++)
#pragma unroll
        for (int c = 0; c < 8; c++) acc[m][c] = 0.f;

    for (int kc = 0; kc < DW; kc += 100) {
        __syncthreads();   // protect previous chunk reads
        for (int i = tid; i < 2500; i += 256) {
            int r = i / 25, c = i % 25;
            float4 v = *(const float4*)&emb[(size_t)(v0 + r) * DW + kc + c * 4];
            *(float4*)&e_s[r * 108 + c * 4] = v;
        }
        __syncthreads();

        if (tid < 250) {
#pragma unroll 2
            for (int kk = 0; kk < 25; kk++) {
                float4 e4[10];
#pragma unroll
                for (int m = 0; m < 10; m++)
                    e4[m] = *(const float4*)&e_s[(m_idx * 10 + m) * 108 + kk * 4];
                const float* wbase = w_T + (size_t)(kc + kk * 4) * G4 + n_idx * 8;
#pragma unroll
                for (int j = 0; j < 4; j++) {
                    float4 wa = *(const float4*)(wbase + j * G4);
                    float4 wb = *(const float4*)(wbase + j * G4 + 4);
#pragma unroll
                    for (int m = 0; m < 10; m++) {
                        float ev = (j == 0) ? e4[m].x : (j == 1) ? e4[m].y
                                 : (j == 2) ? e4[m].z : e4[m].w;
                        acc[m][0] = fmaf(ev, wa.x, acc[m][0]);
                        acc[m][1] = fmaf(ev, wa.y, acc[m][1]);
                        acc[m][2] = fmaf(ev, wa.z, acc[m][2]);
                        acc[m][3] = fmaf(ev, wa.w, acc[m][3]);
                        acc[m][4] = fmaf(ev, wb.x, acc[m][4]);
                        acc[m][5] = fmaf(ev, wb.y, acc[m][5]);
                        acc[m][6] = fmaf(ev, wb.z, acc[m][6]);
                        acc[m][7] = fmaf(ev, wb.w, acc[m][7]);
                    }
                }
            }
        }
    }

    if (tid < 250) {
#pragma unroll
        for (int c = 0; c < 8; c++) {
            int u = n_idx * 8 + c;
            float bias = b_ih[u] + b_hh[u];
            int u2 = (u % DH) * 4 + (u / DH);   // gate-permuted column
#pragma unroll
            for (int m = 0; m < 10; m++)
                emb_proj[(size_t)(v0 + m_idx * 10 + m) * G4 + u2] = acc[m][c] + bias;
        }
    }
}

// ---------------------------------------------------------------------------
// Kernel B (rewritten): 2 waves (128 threads) per batch element.
// Thread tid owns gate columns {2*tid, 2*tid+1} of unit u = tid/2:
//   even threads -> gates (i,f), odd threads -> gates (c,o).
// Per-thread w_hh footprint = 100 floats (fits registers at 2 waves/SIMD;
// the old 1-wave layout needed 208 and the compiler demoted it -> per-step
// reload stalls, VGPR_Count=140 was the evidence). 2048 waves total give
// 2 waves/SIMD of *independent* batches for latency hiding. Gate-pair
// exchange via quad_perm DPP (VALU-speed); both threads of a pair keep
// identical c/h redundantly (zero divergence). h double-buffered in LDS,
// one __syncthreads per step. Gather prefetch depth 3 (float2 per lane,
// coalesced 800B row).
__device__ __forceinline__ float dpp_xor1(float x) {
    // quad_perm [1,0,3,2] : lane 0<->1, 2<->3 within each quad
    return __int_as_float(__builtin_amdgcn_update_dpp(
        0, __float_as_int(x), 0xB1, 0xF, 0xF, true));
}

__global__ __launch_bounds__(128, 2) void lstm_kernel(
    const int* __restrict__ x, const int* __restrict__ lengs,
    const float* __restrict__ emb_proj, const float* __restrict__ w_hh,
    const float* __restrict__ w_out, const float* __restrict__ b_out,
    float* __restrict__ out)
{
    __shared__ __align__(16) float hbuf[2][52];
    __shared__ int x_s[TMAX];
    __shared__ float red[OUTC];

    const int tid = threadIdx.x;
    const int b   = blockIdx.x;
    const int u   = tid >> 1;              // unit 0..63 (>=50 are spares)
    const int uu  = (u < DH) ? u : 0;      // clamp for safe preloads
    const int odd = tid & 1;               // 0: gates i,f ; 1: gates c,o
    const int len = lengs[b];

    for (int i = tid; i < TMAX; i += 128) x_s[i] = x[b * TMAX + i];
    if (tid < 52) hbuf[0][tid] = 0.f;

    // w_hh rows for gates gA=2*odd, gB=2*odd+1 of unit uu -> registers.
    // Rows are 200B-strided => only 8B-aligned: load as float2.
    float wA[DH], wB[DH];
    {
        const float* rA = w_hh + (size_t)((2 * odd) * DH + uu) * DH;
        const float* rB = w_hh + (size_t)((2 * odd + 1) * DH + uu) * DH;
#pragma unroll
        for (int k = 0; k < 25; k++) {
            float2 a  = *(const float2*)(rA + 2 * k);
            float2 bb = *(const float2*)(rB + 2 * k);
            wA[2 * k] = a.x;  wA[2 * k + 1] = a.y;
            wB[2 * k] = bb.x; wB[2 * k + 1] = bb.y;
        }
    }
    __syncthreads();

    // gather columns: unit-major gate-minor layout => cols {4u+2*odd, +1}
    const int col = (u < DH) ? (tid * 2) : 0;
    const float* ep = emb_proj;
    float2 p0 = *(const float2*)(ep + (size_t)x_s[0] * G4 + col);
    float2 p1 = *(const float2*)(ep + (size_t)x_s[1] * G4 + col);
    float2 p2 = *(const float2*)(ep + (size_t)x_s[2] * G4 + col);
    float c_reg = 0.f;

    for (int t = 0; t < len; t++) {
        float2 cur = p0; p0 = p1; p1 = p2;
        int nt = t + 3; nt = (nt < TMAX) ? nt : TMAX - 1;
        p2 = *(const float2*)(ep + (size_t)x_s[nt] * G4 + col);

        const float* hb = hbuf[t & 1];
        // 2 dependency chains per dot (25*4 = 100cy latency instead of 200)
        float accA0 = 0.f, accA1 = 0.f, accB0 = 0.f, accB1 = 0.f;
#pragma unroll
        for (int k4 = 0; k4 < 12; k4++) {
            float4 h4 = *(const float4*)(hb + 4 * k4);
            if ((k4 & 1) == 0) {
                accA0 = fmaf(h4.x, wA[4*k4], fmaf(h4.y, wA[4*k4+1],
                        fmaf(h4.z, wA[4*k4+2], fmaf(h4.w, wA[4*k4+3], accA0))));
                accB0 = fmaf(h4.x, wB[4*k4], fmaf(h4.y, wB[4*k4+1],
                        fmaf(h4.z, wB[4*k4+2], fmaf(h4.w, wB[4*k4+3], accB0))));
            } else {
                accA1 = fmaf(h4.x, wA[4*k4], fmaf(h4.y, wA[4*k4+1],
                        fmaf(h4.z, wA[4*k4+2], fmaf(h4.w, wA[4*k4+3], accA1))));
                accB1 = fmaf(h4.x, wB[4*k4], fmaf(h4.y, wB[4*k4+1],
                        fmaf(h4.z, wB[4*k4+2], fmaf(h4.w, wB[4*k4+3], accB1))));
            }
        }
        {   // tail k = 48,49
            float2 h2 = *(const float2*)(hb + 48);
            accA0 = fmaf(h2.x, wA[48], fmaf(h2.y, wA[49], accA0));
            accB1 = fmaf(h2.x, wB[48], fmaf(h2.y, wB[49], accB1));
        }
        float gA = cur.x + accA0 + accA1;
        float gB = cur.y + accB0 + accB1;

        // even: vA=sig(i), vB=sig(f) ; odd: vA=tanh(c), vB=sig(o)
        // tanh(x) = 2*sigmoid(2x) - 1 (branchless; safe at +-inf)
        float yA = odd ? 2.f * gA : gA;
        float sA = 1.f / (1.f + __expf(-yA));
        float vA = odd ? fmaf(2.f, sA, -1.f) : sA;
        float vB = 1.f / (1.f + __expf(-gB));

        float oA = dpp_xor1(vA);
        float oB = dpp_xor1(vB);
        float si = odd ? oA : vA;
        float sf = odd ? oB : vB;
        float tg = odd ? vA : oA;
        float so = odd ? vB : oB;

        float cn = fmaf(sf, c_reg, si * tg);
        c_reg = cn;                       // identical on both pair threads
        float th = fmaf(2.f, 1.f / (1.f + __expf(-2.f * cn)), -1.f);
        float hn = so * th;
        if (!odd && u < DH) hbuf[(t + 1) & 1][u] = hn;
        __syncthreads();
    }

    // logits + softmax (threads 0-3, all in wave 0: LDS ops program-ordered)
    const float* hf = hbuf[len & 1];
    if (tid < OUTC) {
        float lg = b_out[tid];
        const float* wo = w_out + tid * DH;
#pragma unroll
        for (int k = 0; k < DH; k++) lg = fmaf(hf[k], wo[k], lg);
        red[tid] = lg;
    }
    if (tid < OUTC) {
        float m = fmaxf(fmaxf(red[0], red[1]), fmaxf(red[2], red[3]));
        float s = 0.f;
#pragma unroll
        for (int j = 0; j < OUTC; j++) s += __expf(red[j] - m);
        out[b * OUTC + tid] = __expf(red[tid] - m) / s;
    }
}

// ---------------------------------------------------------------------------
extern "C" void kernel_launch(void* const* d_in, const int* in_sizes, int n_in,
                              void* d_out, int out_size, void* d_ws, size_t ws_size,
                              hipStream_t stream) {
    const int*   x     = (const int*)d_in[0];
    const int*   lengs = (const int*)d_in[1];
    const float* emb   = (const float*)d_in[2];
    const float* w_ih  = (const float*)d_in[3];
    const float* w_hh  = (const float*)d_in[4];
    const float* b_ih  = (const float*)d_in[5];
    const float* b_hh  = (const float*)d_in[6];
    const float* w_out = (const float*)d_in[7];
    const float* b_out = (const float*)d_in[8];
    float* out = (float*)d_out;

    float* emb_proj = (float*)d_ws;                       // 40 MB
    float* w_T      = emb_proj + (size_t)VOCAB * G4;      // +240 KB

    hipLaunchKernelGGL(transpose_wih, dim3((G4 * DW + 255) / 256), dim3(256),
                       0, stream, w_ih, w_T);
    hipLaunchKernelGGL(proj_kernel, dim3(VOCAB / 100), dim3(256), 0, stream,
                       emb, w_T, b_ih, b_hh, emb_proj);
    hipLaunchKernelGGL(lstm_kernel, dim3(BATCH), dim3(128), 0, stream,
                       x, lengs, emb_proj, w_hh, w_out, b_out, out);
}

// Round 2
// 307.080 us; speedup vs baseline: 1.1443x; 1.0776x over previous
//
#include <hip/hip_runtime.h>
#include <math.h>

#define VOCAB 50000
#define DW 300
#define DH 50
#define G4 200
#define BATCH 1024
#define TMAX 200
#define OUTC 4

// ---------------------------------------------------------------------------
// Kernel 0: transpose + gate-permute w_ih [200][300] -> w_T [300][200] with
// columns u2 = (u%50)*4 + u/50 (unit-major, gate-minor). Baking the
// permutation here makes proj's epilogue stores CONTIGUOUS (fixes the 5.4x
// write amplification seen as WRITE_SIZE=216MB for a 40MB output).
__global__ __launch_bounds__(256) void transpose_wih(
    const float* __restrict__ w_ih, float* __restrict__ w_T)
{
    int i = blockIdx.x * 256 + threadIdx.x;
    if (i < G4 * DW) {
        int u = i / DW, k = i % DW;
        int u2 = (u % DH) * 4 + (u / DH);
        w_T[k * G4 + u2] = w_ih[i];
    }
}

// ---------------------------------------------------------------------------
// Kernel A: emb_proj[v][u2] = sum_k emb[v][k]*w_ih[u][k] + b_ih[u] + b_hh[u]
// Columns are already u2-ordered (permuted w_T), so the store is 2 coalesced
// float4s per row. w reads double-buffered in registers: kk+1's 8 float4
// loads issue before kk's 320 FMAs (~640 cyc of cover >> ~250 cyc L2
// latency) — attacks the 32% VALUBusy latency stall.
__global__ __launch_bounds__(256, 2) void proj_kernel(
    const float* __restrict__ emb, const float* __restrict__ w_T,
    const float* __restrict__ b_ih, const float* __restrict__ b_hh,
    float* __restrict__ emb_proj)
{
    __shared__ __align__(16) float e_s[100 * 108];  // rows padded to 108 dwords
    const int tid = threadIdx.x;
    const int v0 = blockIdx.x * 100;
    const int m_idx = tid / 25;   // 0..9 (valid for tid<250)
    const int n_idx = tid % 25;   // 0..24

    float acc[10][8];
#pragma unroll
    for (int m = 0; m < 10; m++)
#pragma unroll
        for (int c = 0; c < 8; c++) acc[m][c] = 0.f;

    const float* wcol = w_T + n_idx * 8;

    for (int kc = 0; kc < DW; kc += 100) {
        __syncthreads();   // protect previous chunk reads
        for (int i = tid; i < 2500; i += 256) {
            int r = i / 25, c = i % 25;
            float4 v = *(const float4*)&emb[(size_t)(v0 + r) * DW + kc + c * 4];
            *(float4*)&e_s[r * 108 + c * 4] = v;
        }
        __syncthreads();

        if (tid < 250) {
            // prime kk=0
            float4 wa[4], wb[4];
#pragma unroll
            for (int j = 0; j < 4; j++) {
                const float* p = wcol + (size_t)(kc + j) * G4;
                wa[j] = *(const float4*)p;
                wb[j] = *(const float4*)(p + 4);
            }
            for (int kk = 0; kk < 25; kk++) {
                // prefetch kk+1 (8 loads in flight across the FMA block)
                float4 na[4], nb[4];
                int kn = kc + ((kk < 24) ? (kk + 1) : kk) * 4;
#pragma unroll
                for (int j = 0; j < 4; j++) {
                    const float* p = wcol + (size_t)(kn + j) * G4;
                    na[j] = *(const float4*)p;
                    nb[j] = *(const float4*)(p + 4);
                }
                float4 e4[10];
#pragma unroll
                for (int m = 0; m < 10; m++)
                    e4[m] = *(const float4*)&e_s[(m_idx * 10 + m) * 108 + kk * 4];
#pragma unroll
                for (int j = 0; j < 4; j++) {
#pragma unroll
                    for (int m = 0; m < 10; m++) {
                        float ev = (j == 0) ? e4[m].x : (j == 1) ? e4[m].y
                                 : (j == 2) ? e4[m].z : e4[m].w;
                        acc[m][0] = fmaf(ev, wa[j].x, acc[m][0]);
                        acc[m][1] = fmaf(ev, wa[j].y, acc[m][1]);
                        acc[m][2] = fmaf(ev, wa[j].z, acc[m][2]);
                        acc[m][3] = fmaf(ev, wa[j].w, acc[m][3]);
                        acc[m][4] = fmaf(ev, wb[j].x, acc[m][4]);
                        acc[m][5] = fmaf(ev, wb[j].y, acc[m][5]);
                        acc[m][6] = fmaf(ev, wb[j].z, acc[m][6]);
                        acc[m][7] = fmaf(ev, wb[j].w, acc[m][7]);
                    }
                }
#pragma unroll
                for (int j = 0; j < 4; j++) { wa[j] = na[j]; wb[j] = nb[j]; }
            }
        }
    }

    if (tid < 250) {
        float bias[8];
#pragma unroll
        for (int c = 0; c < 8; c++) {
            int u2 = n_idx * 8 + c;
            int u  = (u2 & 3) * DH + (u2 >> 2);   // inverse gate permutation
            bias[c] = b_ih[u] + b_hh[u];
        }
#pragma unroll
        for (int m = 0; m < 10; m++) {
            float* dst = &emb_proj[(size_t)(v0 + m_idx * 10 + m) * G4 + n_idx * 8];
            *(float4*)dst = make_float4(acc[m][0] + bias[0], acc[m][1] + bias[1],
                                        acc[m][2] + bias[2], acc[m][3] + bias[3]);
            *(float4*)(dst + 4) = make_float4(acc[m][4] + bias[4], acc[m][5] + bias[5],
                                              acc[m][6] + bias[6], acc[m][7] + bias[7]);
        }
    }
}

// ---------------------------------------------------------------------------
// Kernel B: 2 waves (128 threads) per batch element; thread owns 2 gate rows
// of unit u = tid/2 (even: i,f; odd: c,o). NEW: the 100 w_hh values are
// PINNED in VGPRs via opaque asm (VGPR_Count=68 last round proved the
// compiler rematerialized them in the t-loop -> ~1600 cyc/step of L1 traffic,
// exactly the measured wall). An asm result cannot be rematerialized.
__device__ __forceinline__ float dpp_xor1(float x) {
    // quad_perm [1,0,3,2] : lane 0<->1, 2<->3 within each quad
    return __int_as_float(__builtin_amdgcn_update_dpp(
        0, __float_as_int(x), 0xB1, 0xF, 0xF, true));
}

__global__ __launch_bounds__(128, 2) void lstm_kernel(
    const int* __restrict__ x, const int* __restrict__ lengs,
    const float* __restrict__ emb_proj, const float* __restrict__ w_hh,
    const float* __restrict__ w_out, const float* __restrict__ b_out,
    float* __restrict__ out)
{
    __shared__ __align__(16) float hbuf[2][52];
    __shared__ int x_s[TMAX];
    __shared__ float red[OUTC];

    const int tid = threadIdx.x;
    const int b   = blockIdx.x;
    const int u   = tid >> 1;              // unit 0..63 (>=50 are spares)
    const int uu  = (u < DH) ? u : 0;      // clamp for safe preloads
    const int odd = tid & 1;               // 0: gates i,f ; 1: gates c,o
    const int len = lengs[b];

    for (int i = tid; i < TMAX; i += 128) x_s[i] = x[b * TMAX + i];
    if (tid < 52) hbuf[0][tid] = 0.f;

    // w_hh rows for gates gA=2*odd, gB=2*odd+1 of unit uu -> registers.
    float wA[DH], wB[DH];
    {
        const float* rA = w_hh + (size_t)((2 * odd) * DH + uu) * DH;
        const float* rB = w_hh + (size_t)((2 * odd + 1) * DH + uu) * DH;
#pragma unroll
        for (int k = 0; k < 25; k++) {
            float2 a  = *(const float2*)(rA + 2 * k);
            float2 bb = *(const float2*)(rB + 2 * k);
            wA[2 * k] = a.x;  wA[2 * k + 1] = a.y;
            wB[2 * k] = bb.x; wB[2 * k + 1] = bb.y;
        }
    }
    // Pin: opaque asm defeats rematerialization; values must stay in VGPRs.
#pragma unroll
    for (int k = 0; k < DH; k++) {
        asm volatile("" : "+v"(wA[k]));
        asm volatile("" : "+v"(wB[k]));
    }
    __syncthreads();

    // gather columns: unit-major gate-minor layout => cols {4u+2*odd, +1}
    const int col = (u < DH) ? (tid * 2) : 0;
    const float* ep = emb_proj;
    float2 p0 = *(const float2*)(ep + (size_t)x_s[0] * G4 + col);
    float2 p1 = *(const float2*)(ep + (size_t)x_s[1] * G4 + col);
    float2 p2 = *(const float2*)(ep + (size_t)x_s[2] * G4 + col);
    float c_reg = 0.f;

    for (int t = 0; t < len; t++) {
        float2 cur = p0; p0 = p1; p1 = p2;
        int nt = t + 3; nt = (nt < TMAX) ? nt : TMAX - 1;
        p2 = *(const float2*)(ep + (size_t)x_s[nt] * G4 + col);

        const float* hb = hbuf[t & 1];
        // 2 dependency chains per dot (25*4 = 100cy latency instead of 200)
        float accA0 = 0.f, accA1 = 0.f, accB0 = 0.f, accB1 = 0.f;
#pragma unroll
        for (int k4 = 0; k4 < 12; k4++) {
            float4 h4 = *(const float4*)(hb + 4 * k4);
            if ((k4 & 1) == 0) {
                accA0 = fmaf(h4.x, wA[4*k4], fmaf(h4.y, wA[4*k4+1],
                        fmaf(h4.z, wA[4*k4+2], fmaf(h4.w, wA[4*k4+3], accA0))));
                accB0 = fmaf(h4.x, wB[4*k4], fmaf(h4.y, wB[4*k4+1],
                        fmaf(h4.z, wB[4*k4+2], fmaf(h4.w, wB[4*k4+3], accB0))));
            } else {
                accA1 = fmaf(h4.x, wA[4*k4], fmaf(h4.y, wA[4*k4+1],
                        fmaf(h4.z, wA[4*k4+2], fmaf(h4.w, wA[4*k4+3], accA1))));
                accB1 = fmaf(h4.x, wB[4*k4], fmaf(h4.y, wB[4*k4+1],
                        fmaf(h4.z, wB[4*k4+2], fmaf(h4.w, wB[4*k4+3], accB1))));
            }
        }
        {   // tail k = 48,49
            float2 h2 = *(const float2*)(hb + 48);
            accA0 = fmaf(h2.x, wA[48], fmaf(h2.y, wA[49], accA0));
            accB1 = fmaf(h2.x, wB[48], fmaf(h2.y, wB[49], accB1));
        }
        float gA = cur.x + accA0 + accA1;
        float gB = cur.y + accB0 + accB1;

        // even: vA=sig(i), vB=sig(f) ; odd: vA=tanh(c), vB=sig(o)
        float yA = odd ? 2.f * gA : gA;
        float sA = 1.f / (1.f + __expf(-yA));
        float vA = odd ? fmaf(2.f, sA, -1.f) : sA;
        float vB = 1.f / (1.f + __expf(-gB));

        float oA = dpp_xor1(vA);
        float oB = dpp_xor1(vB);
        float si = odd ? oA : vA;
        float sf = odd ? oB : vB;
        float tg = odd ? vA : oA;
        float so = odd ? vB : oB;

        float cn = fmaf(sf, c_reg, si * tg);
        c_reg = cn;                       // identical on both pair threads
        float th = fmaf(2.f, 1.f / (1.f + __expf(-2.f * cn)), -1.f);
        float hn = so * th;
        if (!odd && u < DH) hbuf[(t + 1) & 1][u] = hn;
        __syncthreads();
    }

    // logits + softmax (threads 0-3, all in wave 0: LDS ops program-ordered)
    const float* hf = hbuf[len & 1];
    if (tid < OUTC) {
        float lg = b_out[tid];
        const float* wo = w_out + tid * DH;
#pragma unroll
        for (int k = 0; k < DH; k++) lg = fmaf(hf[k], wo[k], lg);
        red[tid] = lg;
    }
    if (tid < OUTC) {
        float m = fmaxf(fmaxf(red[0], red[1]), fmaxf(red[2], red[3]));
        float s = 0.f;
#pragma unroll
        for (int j = 0; j < OUTC; j++) s += __expf(red[j] - m);
        out[b * OUTC + tid] = __expf(red[tid] - m) / s;
    }
}

// ---------------------------------------------------------------------------
extern "C" void kernel_launch(void* const* d_in, const int* in_sizes, int n_in,
                              void* d_out, int out_size, void* d_ws, size_t ws_size,
                              hipStream_t stream) {
    const int*   x     = (const int*)d_in[0];
    const int*   lengs = (const int*)d_in[1];
    const float* emb   = (const float*)d_in[2];
    const float* w_ih  = (const float*)d_in[3];
    const float* w_hh  = (const float*)d_in[4];
    const float* b_ih  = (const float*)d_in[5];
    const float* b_hh  = (const float*)d_in[6];
    const float* w_out = (const float*)d_in[7];
    const float* b_out = (const float*)d_in[8];
    float* out = (float*)d_out;

    float* emb_proj = (float*)d_ws;                       // 40 MB
    float* w_T      = emb_proj + (size_t)VOCAB * G4;      // +240 KB

    hipLaunchKernelGGL(transpose_wih, dim3((G4 * DW + 255) / 256), dim3(256),
                       0, stream, w_ih, w_T);
    hipLaunchKernelGGL(proj_kernel, dim3(VOCAB / 100), dim3(256), 0, stream,
                       emb, w_T, b_ih, b_hh, emb_proj);
    hipLaunchKernelGGL(lstm_kernel, dim3(BATCH), dim3(128), 0, stream,
                       x, lengs, emb_proj, w_hh, w_out, b_out, out);
}